// Round 3
// baseline (295.894 us; speedup 1.0000x reference)
//
#include <hip/hip_runtime.h>
#include <hip/hip_bf16.h>

typedef float v4f __attribute__((ext_vector_type(4)));
typedef short v8s __attribute__((ext_vector_type(8)));

// ---- workspace layout ----
// float indices:
#define WS_STAT2   0        // 64   conv2 per-ic mean-of-max
#define WS_STATL   64       // 1024 linear per-feature sum
#define WS_B1      1088     // 64
#define WS_B2      1152     // 64
#define WS_WL      1216     // 10240
#define WS_BL      11456    // 10
#define WS_IMAX    11520    // 2048 per-image max|x|
// byte offsets:
#define WS_W1F_B   54272    // 4096 bf16 conv1 weight frags [ot][q][m16][j]
#define WS_WP2_B   62464    // 25*64*64 bf16 conv2 weights [uv][oc][ic]
#define WS_P1_B    267264   // 2048*144*64 bf16 pooled1 NHWC
#define WS_P2_B    38016000 // 2048*1024 fp32 pooled2
// total ~46.4 MB

// per-image max|x|: 512 blocks x 4 waves, wave = 1 image. First blocks zero stat accum.
__global__ void k_stat1(const float* __restrict__ x, float* ws) {
    int tid = threadIdx.x;
    int flat = blockIdx.x * 256 + tid;
    if (flat < 1088) ws[flat] = 0.f;  // WS_STAT2 + WS_STATL
    int wv = tid >> 6, lane = tid & 63;
    int n = blockIdx.x * 4 + wv;
    const float* p = x + n * 784;
    float m = 0.f;
    for (int i = lane; i < 784; i += 64) m = fmaxf(m, fabsf(p[i]));
#pragma unroll
    for (int off = 32; off; off >>= 1) m = fmaxf(m, __shfl_xor(m, off, 64));
    if (lane == 0) ws[WS_IMAX + n] = m;
}

// conv1 SCINOL weights -> bf16 B-fragments [ot][q][m16][j] (taps>=25 zeroed), bias fp32
__global__ void k_prepw1(const float* __restrict__ w0, const float* __restrict__ S2,
                         const float* __restrict__ G, const float* __restrict__ eta,
                         const float* __restrict__ wM,
                         const float* __restrict__ b0, const float* __restrict__ bS2,
                         const float* __restrict__ bG, const float* __restrict__ beta,
                         float* ws) {
    __shared__ float red[256];
    int tid = threadIdx.x;
    float p = 0.f;
    for (int i = tid; i < 2048; i += 256) p += ws[WS_IMAX + i];
    red[tid] = p;
    __syncthreads();
    for (int s = 128; s > 0; s >>= 1) {
        if (tid < s) red[tid] += red[tid + s];
        __syncthreads();
    }
    float M = fmaxf(red[0] * (1.f / 2048.f), wM[0]);

    int i = blockIdx.x * 256 + tid;
    if (i < 4096) {
        int j = i & 7, m16 = (i >> 3) & 15, q = (i >> 7) & 3, ot = i >> 9;
        int tap = q * 8 + j, oc = ot * 16 + m16;
        float v = 0.f;
        if (tap < 25) {
            int s = oc * 25 + tap;
            float g = G[s];
            float den = sqrtf(S2[s] + M * M);
            float inv = 1.f / den;
            float th = fminf(fmaxf(g * inv, -1.f), 1.f);
            v = w0[s] + ((g != 0.f) ? th * 0.5f * inv * eta[s] : 0.f);
        }
        ((__hip_bfloat16*)((char*)ws + WS_W1F_B))[i] = __float2bfloat16(v);
    } else if (i < 4160) {
        int c = i - 4096;
        float g = bG[c];
        float den = sqrtf(bS2[c] + 1.f);
        float inv = 1.f / den;
        float th = fminf(fmaxf(g * inv, -1.f), 1.f);
        ws[WS_B1 + c] = b0[c] + ((g != 0.f) ? th * 0.5f * inv * beta[c] : 0.f);
    }
}

// conv1 via MFMA implicit GEMM. Block = 256 thr (4 waves) = 1 image.
// Pixels in pooled-window order -> in-register 2x2 maxpool on the D-fragment.
__global__ void __launch_bounds__(256, 6)
k_conv1(const float* __restrict__ x, float* ws, __hip_bfloat16* __restrict__ pool1) {
    __shared__ __align__(16) float sX[1024];   // 28x28 image + zero pad
    __shared__ int sMax[64];
    int n = blockIdx.x, tid = threadIdx.x;
    int wv = tid >> 6, lane = tid & 63;
    int m16 = lane & 15, quad = lane >> 4;

    {   // stage image (784 floats) + zero pad to 1024
        const float4* src = (const float4*)(x + (size_t)n * 784);
        float4 v = {0.f, 0.f, 0.f, 0.f};
        if (tid < 196) v = src[tid];
        ((float4*)sX)[tid] = v;
    }
    if (tid < 64) sMax[tid] = 0;

    const ushort* wfrag = (const ushort*)((const char*)ws + WS_W1F_B);
    v8s bfr[4];
    float bias[4];
#pragma unroll
    for (int ot = 0; ot < 4; ++ot) {
        bfr[ot] = *(const v8s*)(wfrag + ((ot * 4 + quad) * 16 + m16) * 8);
        bias[ot] = ws[WS_B1 + ot * 16 + m16];
    }

    // tap offsets for this quad: taps q*8..q*8+7, delta = tap + 23*u (u = tap/5)
    int dj[8];
#pragma unroll
    for (int j = 0; j < 8; ++j) {
        int tap = quad * 8 + j;
        int u = (tap * 13) >> 6;
        dj[j] = tap + 23 * u;
    }

    // A-side pixel coords: P = MT*16 + m16 -> window = MT*4 + (m16>>2), corner = m16&3
    int W0 = wv * 36 + (m16 >> 2);
    int wy = (W0 * 171) >> 11;
    int wx = W0 - wy * 12;
    int coff = 28 * ((m16 >> 1) & 1) + (m16 & 1);

    __syncthreads();

    float vmax[4] = {0.f, 0.f, 0.f, 0.f};
    __hip_bfloat16* op = pool1 + (size_t)n * 9216;
    for (int mt = 0; mt < 9; ++mt) {
        int base = 56 * wy + 2 * wx + coff;
        union { v8s v; ushort us[8]; } ua;
#pragma unroll
        for (int j = 0; j < 8; ++j)
            ua.us[j] = __bfloat16_as_ushort(__float2bfloat16(sX[base + dj[j]]));

        v4f z = {0.f, 0.f, 0.f, 0.f};
        v4f acc[4];
#pragma unroll
        for (int ot = 0; ot < 4; ++ot)
            acc[ot] = __builtin_amdgcn_mfma_f32_16x16x32_bf16(ua.v, bfr[ot], z, 0, 0, 0);

        int Wd = (wv * 9 + mt) * 4 + quad;
#pragma unroll
        for (int ot = 0; ot < 4; ++ot) {
            v4f a = acc[ot];
            float m = fmaxf(fmaxf(a[0], a[1]), fmaxf(a[2], a[3]));
            float pv = fmaxf(m + bias[ot], 0.f);
            vmax[ot] = fmaxf(vmax[ot], pv);
            op[Wd * 64 + ot * 16 + m16] = __float2bfloat16(pv);
        }
        wx += 4;
        if (wx >= 12) { wx -= 12; ++wy; }
    }

#pragma unroll
    for (int ot = 0; ot < 4; ++ot) {
        float m = vmax[ot];
        m = fmaxf(m, __shfl_xor(m, 16, 64));
        m = fmaxf(m, __shfl_xor(m, 32, 64));
        if (lane < 16) atomicMax(&sMax[ot * 16 + lane], __float_as_int(m));
    }
    __syncthreads();
    if (tid < 64) atomicAdd(&ws[WS_STAT2 + tid], __int_as_float(sMax[tid]) * (1.f / 2048.f));
}

// conv2 SCINOL weights -> bf16 [uv][oc][ic]; bias -> ws[WS_B2]
__global__ void k_prepw2(const float* __restrict__ w0, const float* __restrict__ S2,
                         const float* __restrict__ G, const float* __restrict__ eta,
                         const float* __restrict__ wM,
                         const float* __restrict__ b0, const float* __restrict__ bS2,
                         const float* __restrict__ bG, const float* __restrict__ beta,
                         float* ws, __hip_bfloat16* __restrict__ wp2) {
    int i = blockIdx.x * 256 + threadIdx.x;  // exactly 102400
    int uv = i >> 12, rem = i & 4095, oc = rem >> 6, ic = rem & 63;
    int s = oc * 1600 + ic * 25 + uv;
    float M = fmaxf(ws[WS_STAT2 + ic], wM[ic]);
    float g = G[s];
    float den = sqrtf(S2[s] + M * M);
    float inv = 1.f / den;
    float th = fminf(fmaxf(g * inv, -1.f), 1.f);
    float v = w0[s] + ((g != 0.f) ? th * 0.5f * inv * eta[s] : 0.f);
    wp2[i] = __float2bfloat16(v);
    if (blockIdx.x == 0 && threadIdx.x < 64) {
        int c = threadIdx.x;
        float gb = bG[c];
        float den2 = sqrtf(bS2[c] + 1.f);
        float inv2 = 1.f / den2;
        float th2 = fminf(fmaxf(gb * inv2, -1.f), 1.f);
        ws[WS_B2 + c] = b0[c] + ((gb != 0.f) ? th2 * 0.5f * inv2 * beta[c] : 0.f);
    }
}

// conv2 implicit GEMM. Block = 128 thr (2 waves) = 2 images, wave = 1 image.
// A from LDS (row stride padded 64->72 ushorts: conflict-free), B-fragments
// straight from global (L1-cached, same 8KB slice for every wave), no in-loop barriers.
__global__ void __launch_bounds__(128, 2)
k_conv2(const ushort* __restrict__ pool1, const ushort* __restrict__ wp2,
        const float* __restrict__ ws, float* __restrict__ pool2) {
    __shared__ __align__(16) ushort sImg[2 * 10368];  // 2 images, 144 rows x 72 (pad)
    int tid = threadIdx.x;
    int wv = tid >> 6, lane = tid & 63;
    int n0 = blockIdx.x * 2;

    {   // stage 2 images: 288 rows x 8 uint4 chunks, padded dst stride 9 uint4
        const uint4* src = (const uint4*)(pool1 + (size_t)n0 * 9216);
        uint4* dst = (uint4*)sImg;
#pragma unroll
        for (int i = 0; i < 18; ++i) {
            int c = tid + i * 128;          // 0..2303
            int r = c >> 3, col = c & 7;
            dst[r * 9 + col] = src[c];
        }
    }

    int m16 = lane & 15, quad = lane >> 4;
    int q8 = quad * 8;
    int x0 = m16 & 7;
    int yb = m16 >> 3;
    v4f acc[4][4];
#pragma unroll
    for (int i = 0; i < 4; ++i)
#pragma unroll
        for (int j = 0; j < 4; ++j) acc[i][j] = (v4f){0.f, 0.f, 0.f, 0.f};

    __syncthreads();

    const ushort* simg = sImg + wv * 10368;
    const ushort* wbase = wp2 + (m16 * 64 + q8);
    for (int uvIdx = 0; uvIdx < 25; ++uvIdx) {
        int u = (uvIdx * 13) >> 6;       // uvIdx / 5
        int v = uvIdx - u * 5;
        v8s a[2][4], bf[2][4];
#pragma unroll
        for (int kc = 0; kc < 2; ++kc)
#pragma unroll
            for (int pt = 0; pt < 4; ++pt)
                a[kc][pt] = *(const v8s*)(simg +
                    ((pt * 2 + yb + u) * 12 + x0 + v) * 72 + kc * 32 + q8);
        const ushort* wtap = wbase + uvIdx * 4096;
#pragma unroll
        for (int kc = 0; kc < 2; ++kc)
#pragma unroll
            for (int ot = 0; ot < 4; ++ot)
                bf[kc][ot] = *(const v8s*)(wtap + ot * 1024 + kc * 32);
#pragma unroll
        for (int kc = 0; kc < 2; ++kc)
#pragma unroll
            for (int pt = 0; pt < 4; ++pt)
#pragma unroll
                for (int ot = 0; ot < 4; ++ot)
                    acc[pt][ot] = __builtin_amdgcn_mfma_f32_16x16x32_bf16(
                        a[kc][pt], bf[kc][ot], acc[pt][ot], 0, 0, 0);
    }

    // epilogue: bias + relu + 2x2 maxpool -> pooled2[n][oc*16+py*4+px] fp32
    int n = n0 + wv;
    float bv[4];
#pragma unroll
    for (int ot = 0; ot < 4; ++ot) bv[ot] = ws[WS_B2 + ot * 16 + m16];
    float* outp = pool2 + (size_t)n * 1024;
#pragma unroll
    for (int pt = 0; pt < 4; ++pt)
#pragma unroll
        for (int ot = 0; ot < 4; ++ot) {
            v4f a = acc[pt][ot];
            float m01 = fmaxf(a[0], a[1]);
            float m23 = fmaxf(a[2], a[3]);
            m01 = fmaxf(m01, __shfl_xor(m01, 32, 64));
            m23 = fmaxf(m23, __shfl_xor(m23, 32, 64));
            if (lane < 32) {
                int oc = ot * 16 + m16;
                int f = oc * 16 + pt * 4 + (quad & 1) * 2;
                outp[f] = fmaxf(m01 + bv[ot], 0.f);
                outp[f + 1] = fmaxf(m23 + bv[ot], 0.f);
            }
        }
}

// per-feature sum over batch (h >= 0 so |h| = h); 256 blocks x 8 images
__global__ void k_statl(const float* __restrict__ pool2, float* ws) {
    int b = blockIdx.x, tid = threadIdx.x;
    float4 s = {0.f, 0.f, 0.f, 0.f};
    for (int im = 0; im < 8; ++im) {
        float4 v = ((const float4*)(pool2 + (size_t)(b * 8 + im) * 1024))[tid];
        s.x += v.x; s.y += v.y; s.z += v.z; s.w += v.w;
    }
    atomicAdd(&ws[WS_STATL + tid * 4 + 0], s.x);
    atomicAdd(&ws[WS_STATL + tid * 4 + 1], s.y);
    atomicAdd(&ws[WS_STATL + tid * 4 + 2], s.z);
    atomicAdd(&ws[WS_STATL + tid * 4 + 3], s.w);
}

__global__ void k_prepwl(const float* __restrict__ w0, const float* __restrict__ S2,
                         const float* __restrict__ G, const float* __restrict__ eta,
                         const float* __restrict__ wM,
                         const float* __restrict__ b0, const float* __restrict__ bS2,
                         const float* __restrict__ bG, const float* __restrict__ beta,
                         float* ws) {
    int i = blockIdx.x * 256 + threadIdx.x;
    if (i < 10240) {
        int f = i & 1023;
        float stat = ws[WS_STATL + f] * (1.f / 2048.f);
        float M = fmaxf(wM[i], stat);
        float s2 = S2[i];
        float den = sqrtf(s2 + M * M);
        float inv = 1.f / den;
        float th = fminf(fmaxf(G[i] * inv, -1.f), 1.f);
        ws[WS_WL + i] = w0[i] + ((s2 != 0.f) ? th * 0.5f * inv * eta[i] : 0.f);  // cond = wS2 != 0
    } else if (i < 10250) {
        int c = i - 10240;
        float s2 = bS2[c];
        float den = sqrtf(s2 + 1.f);
        float inv = 1.f / den;
        float th = fminf(fmaxf(bG[c] * inv, -1.f), 1.f);
        ws[WS_BL + c] = b0[c] + ((s2 != 0.f) ? th * 0.5f * inv * beta[c] : 0.f);  // cond = bS2 != 0
    }
}

// (2048,1024) x (1024,10)^T + b: wave per image, lane-strided features
__global__ void k_linear(const float* __restrict__ pool2, const float* __restrict__ ws,
                         float* __restrict__ out) {
    int tid = threadIdx.x;
    int wv = tid >> 6, lane = tid & 63;
    int n = blockIdx.x * 4 + wv;
    const float* hp = pool2 + (size_t)n * 1024;
    float h[16];
#pragma unroll
    for (int j = 0; j < 16; ++j) h[j] = hp[j * 64 + lane];
    for (int oc = 0; oc < 10; ++oc) {
        const float* wp = ws + WS_WL + oc * 1024;
        float d = 0.f;
#pragma unroll
        for (int j = 0; j < 16; ++j) d = fmaf(h[j], wp[j * 64 + lane], d);
#pragma unroll
        for (int off = 32; off; off >>= 1) d += __shfl_xor(d, off, 64);
        if (lane == 0) out[n * 10 + oc] = d + ws[WS_BL + oc];
    }
}

extern "C" void kernel_launch(void* const* d_in, const int* in_sizes, int n_in,
                              void* d_out, int out_size, void* d_ws, size_t ws_size,
                              hipStream_t stream) {
    const float* x = (const float*)d_in[0];
    float* ws = (float*)d_ws;
    __hip_bfloat16* wp2 = (__hip_bfloat16*)((char*)d_ws + WS_WP2_B);
    __hip_bfloat16* p1 = (__hip_bfloat16*)((char*)d_ws + WS_P1_B);
    float* p2 = (float*)((char*)d_ws + WS_P2_B);
    float* out = (float*)d_out;

    k_stat1<<<512, 256, 0, stream>>>(x, ws);
    k_prepw1<<<17, 256, 0, stream>>>(
        (const float*)d_in[1], (const float*)d_in[2], (const float*)d_in[3],
        (const float*)d_in[4], (const float*)d_in[5], (const float*)d_in[6],
        (const float*)d_in[7], (const float*)d_in[8], (const float*)d_in[9], ws);
    k_conv1<<<2048, 256, 0, stream>>>(x, ws, p1);
    k_prepw2<<<400, 256, 0, stream>>>(
        (const float*)d_in[10], (const float*)d_in[11], (const float*)d_in[12],
        (const float*)d_in[13], (const float*)d_in[14], (const float*)d_in[15],
        (const float*)d_in[16], (const float*)d_in[17], (const float*)d_in[18], ws, wp2);
    k_conv2<<<1024, 128, 0, stream>>>((const ushort*)p1, (const ushort*)wp2, ws, p2);
    k_statl<<<256, 256, 0, stream>>>(p2, ws);
    k_prepwl<<<41, 256, 0, stream>>>(
        (const float*)d_in[19], (const float*)d_in[20], (const float*)d_in[21],
        (const float*)d_in[22], (const float*)d_in[23], (const float*)d_in[24],
        (const float*)d_in[25], (const float*)d_in[26], (const float*)d_in[27], ws);
    k_linear<<<512, 256, 0, stream>>>(p2, ws, out);
}

// Round 4
// 265.830 us; speedup vs baseline: 1.1131x; 1.1131x over previous
//
#include <hip/hip_runtime.h>
#include <hip/hip_bf16.h>

typedef float v4f __attribute__((ext_vector_type(4)));
typedef short v8s __attribute__((ext_vector_type(8)));

// ---- workspace layout ----
// float indices:
#define WS_STAT2   0        // 64   conv2 per-ic mean-of-max
#define WS_STATL   64       // 1024 linear per-feature sum
#define WS_B1      1088     // 64
#define WS_B2      1152     // 64
#define WS_WL      1216     // 10240
#define WS_BL      11456    // 10
#define WS_IMAX    11520    // 2048 per-image max|x|
// byte offsets:
#define WS_W1F_B   54272    // 4096 bf16 conv1 weight frags [ot][q][m16][j]
#define WS_WP2_B   62464    // 25*64*64 bf16 conv2 weights, fragment order [uv][kc][ot][quad][m16][j]
#define WS_P1_B    267264   // 2048*144*64 bf16 pooled1 NHWC
#define WS_P2_B    38016000 // 2048*1024 fp32 pooled2
// total ~46.4 MB

// per-image max|x|: 512 blocks x 4 waves, wave = 1 image. First blocks zero stat accum.
__global__ void k_stat1(const float* __restrict__ x, float* ws) {
    int tid = threadIdx.x;
    int flat = blockIdx.x * 256 + tid;
    if (flat < 1088) ws[flat] = 0.f;  // WS_STAT2 + WS_STATL
    int wv = tid >> 6, lane = tid & 63;
    int n = blockIdx.x * 4 + wv;
    const float* p = x + n * 784;
    float m = 0.f;
    for (int i = lane; i < 784; i += 64) m = fmaxf(m, fabsf(p[i]));
#pragma unroll
    for (int off = 32; off; off >>= 1) m = fmaxf(m, __shfl_xor(m, off, 64));
    if (lane == 0) ws[WS_IMAX + n] = m;
}

// conv1 SCINOL weights -> bf16 B-fragments [ot][q][m16][j] (taps>=25 zeroed), bias fp32
__global__ void k_prepw1(const float* __restrict__ w0, const float* __restrict__ S2,
                         const float* __restrict__ G, const float* __restrict__ eta,
                         const float* __restrict__ wM,
                         const float* __restrict__ b0, const float* __restrict__ bS2,
                         const float* __restrict__ bG, const float* __restrict__ beta,
                         float* ws) {
    __shared__ float red[256];
    int tid = threadIdx.x;
    float p = 0.f;
    for (int i = tid; i < 2048; i += 256) p += ws[WS_IMAX + i];
    red[tid] = p;
    __syncthreads();
    for (int s = 128; s > 0; s >>= 1) {
        if (tid < s) red[tid] += red[tid + s];
        __syncthreads();
    }
    float M = fmaxf(red[0] * (1.f / 2048.f), wM[0]);

    int i = blockIdx.x * 256 + tid;
    if (i < 4096) {
        int j = i & 7, m16 = (i >> 3) & 15, q = (i >> 7) & 3, ot = i >> 9;
        int tap = q * 8 + j, oc = ot * 16 + m16;
        float v = 0.f;
        if (tap < 25) {
            int s = oc * 25 + tap;
            float g = G[s];
            float den = sqrtf(S2[s] + M * M);
            float inv = 1.f / den;
            float th = fminf(fmaxf(g * inv, -1.f), 1.f);
            v = w0[s] + ((g != 0.f) ? th * 0.5f * inv * eta[s] : 0.f);
        }
        ((__hip_bfloat16*)((char*)ws + WS_W1F_B))[i] = __float2bfloat16(v);
    } else if (i < 4160) {
        int c = i - 4096;
        float g = bG[c];
        float den = sqrtf(bS2[c] + 1.f);
        float inv = 1.f / den;
        float th = fminf(fmaxf(g * inv, -1.f), 1.f);
        ws[WS_B1 + c] = b0[c] + ((g != 0.f) ? th * 0.5f * inv * beta[c] : 0.f);
    }
}

// conv1 via MFMA implicit GEMM. Block = 256 thr (4 waves) = 1 image.
// Pixels in pooled-window order -> in-register 2x2 maxpool on the D-fragment.
__global__ void __launch_bounds__(256, 6)
k_conv1(const float* __restrict__ x, float* ws, __hip_bfloat16* __restrict__ pool1) {
    __shared__ __align__(16) float sX[1024];   // 28x28 image + zero pad
    __shared__ int sMax[64];
    int n = blockIdx.x, tid = threadIdx.x;
    int wv = tid >> 6, lane = tid & 63;
    int m16 = lane & 15, quad = lane >> 4;

    {   // stage image (784 floats) + zero pad to 1024
        const float4* src = (const float4*)(x + (size_t)n * 784);
        float4 v = {0.f, 0.f, 0.f, 0.f};
        if (tid < 196) v = src[tid];
        ((float4*)sX)[tid] = v;
    }
    if (tid < 64) sMax[tid] = 0;

    const ushort* wfrag = (const ushort*)((const char*)ws + WS_W1F_B);
    v8s bfr[4];
    float bias[4];
#pragma unroll
    for (int ot = 0; ot < 4; ++ot) {
        bfr[ot] = *(const v8s*)(wfrag + ((ot * 4 + quad) * 16 + m16) * 8);
        bias[ot] = ws[WS_B1 + ot * 16 + m16];
    }

    // tap offsets for this quad: taps q*8..q*8+7, delta = tap + 23*u (u = tap/5)
    int dj[8];
#pragma unroll
    for (int j = 0; j < 8; ++j) {
        int tap = quad * 8 + j;
        int u = (tap * 13) >> 6;
        dj[j] = tap + 23 * u;
    }

    // A-side pixel coords: P = MT*16 + m16 -> window = MT*4 + (m16>>2), corner = m16&3
    int W0 = wv * 36 + (m16 >> 2);
    int wy = (W0 * 171) >> 11;
    int wx = W0 - wy * 12;
    int coff = 28 * ((m16 >> 1) & 1) + (m16 & 1);

    __syncthreads();

    float vmax[4] = {0.f, 0.f, 0.f, 0.f};
    __hip_bfloat16* op = pool1 + (size_t)n * 9216;
    for (int mt = 0; mt < 9; ++mt) {
        int base = 56 * wy + 2 * wx + coff;
        union { v8s v; ushort us[8]; } ua;
#pragma unroll
        for (int j = 0; j < 8; ++j)
            ua.us[j] = __bfloat16_as_ushort(__float2bfloat16(sX[base + dj[j]]));

        v4f z = {0.f, 0.f, 0.f, 0.f};
        v4f acc[4];
#pragma unroll
        for (int ot = 0; ot < 4; ++ot)
            acc[ot] = __builtin_amdgcn_mfma_f32_16x16x32_bf16(ua.v, bfr[ot], z, 0, 0, 0);

        int Wd = (wv * 9 + mt) * 4 + quad;
#pragma unroll
        for (int ot = 0; ot < 4; ++ot) {
            v4f a = acc[ot];
            float m = fmaxf(fmaxf(a[0], a[1]), fmaxf(a[2], a[3]));
            float pv = fmaxf(m + bias[ot], 0.f);
            vmax[ot] = fmaxf(vmax[ot], pv);
            op[Wd * 64 + ot * 16 + m16] = __float2bfloat16(pv);
        }
        wx += 4;
        if (wx >= 12) { wx -= 12; ++wy; }
    }

#pragma unroll
    for (int ot = 0; ot < 4; ++ot) {
        float m = vmax[ot];
        m = fmaxf(m, __shfl_xor(m, 16, 64));
        m = fmaxf(m, __shfl_xor(m, 32, 64));
        if (lane < 16) atomicMax(&sMax[ot * 16 + lane], __float_as_int(m));
    }
    __syncthreads();
    if (tid < 64) atomicAdd(&ws[WS_STAT2 + tid], __int_as_float(sMax[tid]) * (1.f / 2048.f));
}

// conv2 SCINOL weights -> bf16 in MFMA fragment order [uv][kc][ot][quad][m16][j]
__global__ void k_prepw2(const float* __restrict__ w0, const float* __restrict__ S2,
                         const float* __restrict__ G, const float* __restrict__ eta,
                         const float* __restrict__ wM,
                         const float* __restrict__ b0, const float* __restrict__ bS2,
                         const float* __restrict__ bG, const float* __restrict__ beta,
                         float* ws, __hip_bfloat16* __restrict__ wp2) {
    int i = blockIdx.x * 256 + threadIdx.x;  // exactly 102400
    int j = i & 7, m16 = (i >> 3) & 15, quad = (i >> 7) & 3;
    int ot = (i >> 9) & 3, kc = (i >> 11) & 1, uv = i >> 12;
    int oc = ot * 16 + m16, ic = kc * 32 + quad * 8 + j;
    int s = oc * 1600 + ic * 25 + uv;
    float M = fmaxf(ws[WS_STAT2 + ic], wM[ic]);
    float g = G[s];
    float den = sqrtf(S2[s] + M * M);
    float inv = 1.f / den;
    float th = fminf(fmaxf(g * inv, -1.f), 1.f);
    float v = w0[s] + ((g != 0.f) ? th * 0.5f * inv * eta[s] : 0.f);
    wp2[i] = __float2bfloat16(v);
    if (blockIdx.x == 0 && threadIdx.x < 64) {
        int c = threadIdx.x;
        float gb = bG[c];
        float den2 = sqrtf(bS2[c] + 1.f);
        float inv2 = 1.f / den2;
        float th2 = fminf(fmaxf(gb * inv2, -1.f), 1.f);
        ws[WS_B2 + c] = b0[c] + ((gb != 0.f) ? th2 * 0.5f * inv2 * beta[c] : 0.f);
    }
}

// async 16B/lane prefetch of one 8KB weight tap into LDS (wave-uniform lds base)
__device__ __forceinline__ void prefetch_tap(const ushort* __restrict__ wp2,
                                             ushort* swbuf, int uv, int wv, int lane) {
    const char* g = (const char*)wp2 + uv * 8192 + wv * 1024 + lane * 16;
    char* l = (char*)swbuf + wv * 1024;
#pragma unroll
    for (int j = 0; j < 4; ++j)
        __builtin_amdgcn_global_load_lds(
            (const __attribute__((address_space(1))) unsigned*)(g + j * 2048),
            (__attribute__((address_space(3))) unsigned*)(l + j * 2048),
            16, 0, 0);
}

// conv2 implicit GEMM. Block = 128 thr (2 waves) = 2 images, wave = 1 image.
// A from LDS (padded stride 72), B double-buffered in LDS via async global_load_lds,
// fragment-order weight layout -> conflict-free B reads; one barrier per uv.
__global__ void __launch_bounds__(128)
k_conv2(const ushort* __restrict__ pool1, const ushort* __restrict__ wp2,
        const float* __restrict__ ws, float* __restrict__ pool2) {
    __shared__ __align__(16) ushort sImg[2 * 10368];  // 2 images, 144 rows x 72 (pad)
    __shared__ __align__(16) ushort sW[2][4096];      // double-buffered tap
    int tid = threadIdx.x;
    int wv = tid >> 6, lane = tid & 63;
    int n0 = blockIdx.x * 2;

    {   // stage 2 images: 288 rows x 8 uint4 chunks, padded dst stride 9 uint4
        const uint4* src = (const uint4*)(pool1 + (size_t)n0 * 9216);
        uint4* dst = (uint4*)sImg;
#pragma unroll
        for (int i = 0; i < 18; ++i) {
            int c = tid + i * 128;          // 0..2303
            dst[(c >> 3) * 9 + (c & 7)] = src[c];
        }
    }
    prefetch_tap(wp2, sW[0], 0, wv, lane);

    int m16 = lane & 15, quad = lane >> 4;
    int q8 = quad * 8;
    int x0 = m16 & 7;
    int yb = m16 >> 3;
    v4f acc[4][4];
#pragma unroll
    for (int i = 0; i < 4; ++i)
#pragma unroll
        for (int j = 0; j < 4; ++j) acc[i][j] = (v4f){0.f, 0.f, 0.f, 0.f};

    __syncthreads();  // drains staging stores + prefetch(0)

    const ushort* simg = sImg + wv * 10368;
    for (int uvIdx = 0; uvIdx < 25; ++uvIdx) {
        if (uvIdx < 24) prefetch_tap(wp2, sW[(uvIdx + 1) & 1], uvIdx + 1, wv, lane);
        int u = (uvIdx * 13) >> 6;       // uvIdx / 5
        int v = uvIdx - u * 5;
        v8s a[2][4], bf[2][4];
#pragma unroll
        for (int kc = 0; kc < 2; ++kc)
#pragma unroll
            for (int pt = 0; pt < 4; ++pt)
                a[kc][pt] = *(const v8s*)(simg +
                    ((pt * 2 + yb + u) * 12 + x0 + v) * 72 + kc * 32 + q8);
        const ushort* wb = sW[uvIdx & 1];
#pragma unroll
        for (int kc = 0; kc < 2; ++kc)
#pragma unroll
            for (int ot = 0; ot < 4; ++ot)
                bf[kc][ot] = *(const v8s*)(wb + (((kc * 4 + ot) * 4 + quad) * 16 + m16) * 8);
#pragma unroll
        for (int kc = 0; kc < 2; ++kc)
#pragma unroll
            for (int pt = 0; pt < 4; ++pt)
#pragma unroll
                for (int ot = 0; ot < 4; ++ot)
                    acc[pt][ot] = __builtin_amdgcn_mfma_f32_16x16x32_bf16(
                        a[kc][pt], bf[kc][ot], acc[pt][ot], 0, 0, 0);
        __syncthreads();  // drains prefetch(uv+1); all waves done with sW[uv&1]
    }

    // epilogue: bias + relu + 2x2 maxpool -> pooled2[n][oc*16+py*4+px] fp32
    int n = n0 + wv;
    float bv[4];
#pragma unroll
    for (int ot = 0; ot < 4; ++ot) bv[ot] = ws[WS_B2 + ot * 16 + m16];
    float* outp = pool2 + (size_t)n * 1024;
#pragma unroll
    for (int pt = 0; pt < 4; ++pt)
#pragma unroll
        for (int ot = 0; ot < 4; ++ot) {
            v4f a = acc[pt][ot];
            float m01 = fmaxf(a[0], a[1]);
            float m23 = fmaxf(a[2], a[3]);
            m01 = fmaxf(m01, __shfl_xor(m01, 32, 64));
            m23 = fmaxf(m23, __shfl_xor(m23, 32, 64));
            if (lane < 32) {
                int oc = ot * 16 + m16;
                int f = oc * 16 + pt * 4 + (quad & 1) * 2;
                outp[f] = fmaxf(m01 + bv[ot], 0.f);
                outp[f + 1] = fmaxf(m23 + bv[ot], 0.f);
            }
        }
}

// per-feature sum over batch (h >= 0 so |h| = h); 256 blocks x 8 images
__global__ void k_statl(const float* __restrict__ pool2, float* ws) {
    int b = blockIdx.x, tid = threadIdx.x;
    float4 s = {0.f, 0.f, 0.f, 0.f};
    for (int im = 0; im < 8; ++im) {
        float4 v = ((const float4*)(pool2 + (size_t)(b * 8 + im) * 1024))[tid];
        s.x += v.x; s.y += v.y; s.z += v.z; s.w += v.w;
    }
    atomicAdd(&ws[WS_STATL + tid * 4 + 0], s.x);
    atomicAdd(&ws[WS_STATL + tid * 4 + 1], s.y);
    atomicAdd(&ws[WS_STATL + tid * 4 + 2], s.z);
    atomicAdd(&ws[WS_STATL + tid * 4 + 3], s.w);
}

__global__ void k_prepwl(const float* __restrict__ w0, const float* __restrict__ S2,
                         const float* __restrict__ G, const float* __restrict__ eta,
                         const float* __restrict__ wM,
                         const float* __restrict__ b0, const float* __restrict__ bS2,
                         const float* __restrict__ bG, const float* __restrict__ beta,
                         float* ws) {
    int i = blockIdx.x * 256 + threadIdx.x;
    if (i < 10240) {
        int f = i & 1023;
        float stat = ws[WS_STATL + f] * (1.f / 2048.f);
        float M = fmaxf(wM[i], stat);
        float s2 = S2[i];
        float den = sqrtf(s2 + M * M);
        float inv = 1.f / den;
        float th = fminf(fmaxf(G[i] * inv, -1.f), 1.f);
        ws[WS_WL + i] = w0[i] + ((s2 != 0.f) ? th * 0.5f * inv * eta[i] : 0.f);  // cond = wS2 != 0
    } else if (i < 10250) {
        int c = i - 10240;
        float s2 = bS2[c];
        float den = sqrtf(s2 + 1.f);
        float inv = 1.f / den;
        float th = fminf(fmaxf(bG[c] * inv, -1.f), 1.f);
        ws[WS_BL + c] = b0[c] + ((s2 != 0.f) ? th * 0.5f * inv * beta[c] : 0.f);  // cond = bS2 != 0
    }
}

// (2048,1024) x (1024,10)^T + b: wave per image, lane-strided features
__global__ void k_linear(const float* __restrict__ pool2, const float* __restrict__ ws,
                         float* __restrict__ out) {
    int tid = threadIdx.x;
    int wv = tid >> 6, lane = tid & 63;
    int n = blockIdx.x * 4 + wv;
    const float* hp = pool2 + (size_t)n * 1024;
    float h[16];
#pragma unroll
    for (int j = 0; j < 16; ++j) h[j] = hp[j * 64 + lane];
    for (int oc = 0; oc < 10; ++oc) {
        const float* wp = ws + WS_WL + oc * 1024;
        float d = 0.f;
#pragma unroll
        for (int j = 0; j < 16; ++j) d = fmaf(h[j], wp[j * 64 + lane], d);
#pragma unroll
        for (int off = 32; off; off >>= 1) d += __shfl_xor(d, off, 64);
        if (lane == 0) out[n * 10 + oc] = d + ws[WS_BL + oc];
    }
}

extern "C" void kernel_launch(void* const* d_in, const int* in_sizes, int n_in,
                              void* d_out, int out_size, void* d_ws, size_t ws_size,
                              hipStream_t stream) {
    const float* x = (const float*)d_in[0];
    float* ws = (float*)d_ws;
    __hip_bfloat16* wp2 = (__hip_bfloat16*)((char*)d_ws + WS_WP2_B);
    __hip_bfloat16* p1 = (__hip_bfloat16*)((char*)d_ws + WS_P1_B);
    float* p2 = (float*)((char*)d_ws + WS_P2_B);
    float* out = (float*)d_out;

    k_stat1<<<512, 256, 0, stream>>>(x, ws);
    k_prepw1<<<17, 256, 0, stream>>>(
        (const float*)d_in[1], (const float*)d_in[2], (const float*)d_in[3],
        (const float*)d_in[4], (const float*)d_in[5], (const float*)d_in[6],
        (const float*)d_in[7], (const float*)d_in[8], (const float*)d_in[9], ws);
    k_conv1<<<2048, 256, 0, stream>>>(x, ws, p1);
    k_prepw2<<<400, 256, 0, stream>>>(
        (const float*)d_in[10], (const float*)d_in[11], (const float*)d_in[12],
        (const float*)d_in[13], (const float*)d_in[14], (const float*)d_in[15],
        (const float*)d_in[16], (const float*)d_in[17], (const float*)d_in[18], ws, wp2);
    k_conv2<<<1024, 128, 0, stream>>>((const ushort*)p1, (const ushort*)wp2, ws, p2);
    k_statl<<<256, 256, 0, stream>>>(p2, ws);
    k_prepwl<<<41, 256, 0, stream>>>(
        (const float*)d_in[19], (const float*)d_in[20], (const float*)d_in[21],
        (const float*)d_in[22], (const float*)d_in[23], (const float*)d_in[24],
        (const float*)d_in[25], (const float*)d_in[26], (const float*)d_in[27], ws);
    k_linear<<<512, 256, 0, stream>>>(p2, ws, out);
}

// Round 5
// 220.154 us; speedup vs baseline: 1.3440x; 1.2075x over previous
//
#include <hip/hip_runtime.h>
#include <hip/hip_bf16.h>

typedef float v4f __attribute__((ext_vector_type(4)));
typedef short v8s __attribute__((ext_vector_type(8)));

// ---- workspace layout ----
// float indices:
#define WS_STAT2   0        // 64   conv2 per-ic mean-of-max
#define WS_STATL   64       // 1024 linear per-feature sum (post-reduction)
#define WS_B1      1088     // 64
#define WS_B2      1152     // 64
#define WS_WL      1216     // 10240
#define WS_BL      11456    // 10
#define WS_IMAX    11520    // 2048 per-image max|x|
// byte offsets:
#define WS_W1F_B   54272    // 4096 bf16 conv1 weight frags [ot][q][m16][j], oc = m16*4+ot
#define WS_WP2_B   62464    // 25*64*64 bf16 conv2 weights, fragment order [uv][kc][ot][quad][m16][j]
#define WS_P1_B    267264   // 2048*144*64 bf16 pooled1 NHWC
#define WS_P2_B    38016000 // 2048*1024 fp32 pooled2
// scratch aliases (stream-ordered reuse, no extra footprint):
#define WS_C1MAX_F 9504000  // = P2 base as float idx; conv1 per-image ch-max [n][64]
                            //   (written by conv1, consumed by stat2red BEFORE conv2 writes P2)
#define WS_LPART_F 66816    // = P1 base as float idx; statl partials [64][1024]
                            //   (written by statl AFTER conv2 has consumed P1)
// total ~46.4 MB (unchanged)

// per-image max|x|: 512 blocks x 4 waves, wave = 1 image.
__global__ void k_stat1(const float* __restrict__ x, float* ws) {
    int tid = threadIdx.x;
    int wv = tid >> 6, lane = tid & 63;
    int n = blockIdx.x * 4 + wv;
    const float* p = x + n * 784;
    float m = 0.f;
    for (int i = lane; i < 784; i += 64) m = fmaxf(m, fabsf(p[i]));
#pragma unroll
    for (int off = 32; off; off >>= 1) m = fmaxf(m, __shfl_xor(m, off, 64));
    if (lane == 0) ws[WS_IMAX + n] = m;
}

// conv1 SCINOL weights -> bf16 B-fragments [ot][q][m16][j] with oc = m16*4+ot
// (so conv1's epilogue lane m16 holds 4 CONTIGUOUS channels), bias fp32
__global__ void k_prepw1(const float* __restrict__ w0, const float* __restrict__ S2,
                         const float* __restrict__ G, const float* __restrict__ eta,
                         const float* __restrict__ wM,
                         const float* __restrict__ b0, const float* __restrict__ bS2,
                         const float* __restrict__ bG, const float* __restrict__ beta,
                         float* ws) {
    __shared__ float red[256];
    int tid = threadIdx.x;
    float p = 0.f;
    for (int i = tid; i < 2048; i += 256) p += ws[WS_IMAX + i];
    red[tid] = p;
    __syncthreads();
    for (int s = 128; s > 0; s >>= 1) {
        if (tid < s) red[tid] += red[tid + s];
        __syncthreads();
    }
    float M = fmaxf(red[0] * (1.f / 2048.f), wM[0]);

    int i = blockIdx.x * 256 + tid;
    if (i < 4096) {
        int j = i & 7, m16 = (i >> 3) & 15, q = (i >> 7) & 3, ot = i >> 9;
        int tap = q * 8 + j, oc = m16 * 4 + ot;
        float v = 0.f;
        if (tap < 25) {
            int s = oc * 25 + tap;
            float g = G[s];
            float den = sqrtf(S2[s] + M * M);
            float inv = 1.f / den;
            float th = fminf(fmaxf(g * inv, -1.f), 1.f);
            v = w0[s] + ((g != 0.f) ? th * 0.5f * inv * eta[s] : 0.f);
        }
        ((__hip_bfloat16*)((char*)ws + WS_W1F_B))[i] = __float2bfloat16(v);
    } else if (i < 4160) {
        int c = i - 4096;
        float g = bG[c];
        float den = sqrtf(bS2[c] + 1.f);
        float inv = 1.f / den;
        float th = fminf(fmaxf(g * inv, -1.f), 1.f);
        ws[WS_B1 + c] = b0[c] + ((g != 0.f) ? th * 0.5f * inv * beta[c] : 0.f);
    }
}

// conv1 via MFMA implicit GEMM. Block = 256 thr (4 waves) = 1 image.
// Pixels in pooled-window order -> in-register 2x2 maxpool on the D-fragment.
// Lane m16 owns channels 4*m16..4*m16+3 -> ushort4 coalesced stores.
// NO global atomics: per-image channel maxima go to scratch, reduced by k_stat2red.
__global__ void __launch_bounds__(256)
k_conv1(const float* __restrict__ x, float* ws, __hip_bfloat16* __restrict__ pool1) {
    __shared__ __align__(16) float sX[1024];   // 28x28 image + zero pad
    __shared__ int sMax[64];
    int n = blockIdx.x, tid = threadIdx.x;
    int wv = tid >> 6, lane = tid & 63;
    int m16 = lane & 15, quad = lane >> 4;

    {   // stage image (784 floats) + zero pad to 1024
        const float4* src = (const float4*)(x + (size_t)n * 784);
        float4 v = {0.f, 0.f, 0.f, 0.f};
        if (tid < 196) v = src[tid];
        ((float4*)sX)[tid] = v;
    }
    if (tid < 64) sMax[tid] = 0;

    const ushort* wfrag = (const ushort*)((const char*)ws + WS_W1F_B);
    v8s bfr[4];
#pragma unroll
    for (int ot = 0; ot < 4; ++ot)
        bfr[ot] = *(const v8s*)(wfrag + ((ot * 4 + quad) * 16 + m16) * 8);
    float4 bias = *(const float4*)(ws + WS_B1 + m16 * 4);

    // tap offsets for this quad: taps q*8..q*8+7, delta = tap + 23*u (u = tap/5)
    int dj[8];
#pragma unroll
    for (int j = 0; j < 8; ++j) {
        int tap = quad * 8 + j;
        int u = (tap * 13) >> 6;
        dj[j] = tap + 23 * u;
    }

    // A-side pixel coords: P = MT*16 + m16 -> window = MT*4 + (m16>>2), corner = m16&3
    int W0 = wv * 36 + (m16 >> 2);
    int wy = (W0 * 171) >> 11;
    int wx = W0 - wy * 12;
    int coff = 28 * ((m16 >> 1) & 1) + (m16 & 1);

    __syncthreads();

    float vmax[4] = {0.f, 0.f, 0.f, 0.f};
    ushort* op = (ushort*)(pool1 + (size_t)n * 9216);

    float g[8];
    {
        int base = 56 * wy + 2 * wx + coff;
#pragma unroll
        for (int j = 0; j < 8; ++j) g[j] = sX[base + dj[j]];
    }
    for (int mt = 0; mt < 9; ++mt) {
        union { v8s v; ushort us[8]; } ua;
#pragma unroll
        for (int j = 0; j < 8; ++j)
            ua.us[j] = __bfloat16_as_ushort(__float2bfloat16(g[j]));

        // software-pipeline: issue next iteration's gather before the MFMAs
        wx += 4;
        if (wx >= 12) { wx -= 12; ++wy; }
        if (mt < 8) {
            int nb = 56 * wy + 2 * wx + coff;
#pragma unroll
            for (int j = 0; j < 8; ++j) g[j] = sX[nb + dj[j]];
        }

        v4f z = {0.f, 0.f, 0.f, 0.f};
        v4f acc[4];
#pragma unroll
        for (int ot = 0; ot < 4; ++ot)
            acc[ot] = __builtin_amdgcn_mfma_f32_16x16x32_bf16(ua.v, bfr[ot], z, 0, 0, 0);

        int Wd = (wv * 9 + mt) * 4 + quad;
        ushort4 pk;
#pragma unroll
        for (int ot = 0; ot < 4; ++ot) {
            v4f a = acc[ot];
            float m = fmaxf(fmaxf(a[0], a[1]), fmaxf(a[2], a[3]));
            float pv = fmaxf(m + bias[ot], 0.f);
            vmax[ot] = fmaxf(vmax[ot], pv);
            ((ushort*)&pk)[ot] = __bfloat16_as_ushort(__float2bfloat16(pv));
        }
        *(ushort4*)(op + Wd * 64 + m16 * 4) = pk;  // 8B/lane, 512B/wave contiguous
    }

    // per-channel max: shfl-reduce over quads, LDS atomicMax, then ONE plain
    // global store per channel into scratch [n][64] (no global atomics).
#pragma unroll
    for (int ot = 0; ot < 4; ++ot) {
        float m = vmax[ot];
        m = fmaxf(m, __shfl_xor(m, 16, 64));
        m = fmaxf(m, __shfl_xor(m, 32, 64));
        if (lane < 16) atomicMax(&sMax[lane * 4 + ot], __float_as_int(m));
    }
    __syncthreads();
    if (tid < 64) ws[WS_C1MAX_F + n * 64 + tid] = __int_as_float(sMax[tid]);
}

// reduce conv1 per-image channel maxima -> per-channel batch mean. 64 blocks, 1/ch.
__global__ void k_stat2red(float* ws) {
    __shared__ float red[256];
    int c = blockIdx.x, t = threadIdx.x;
    float s = 0.f;
    for (int n = t; n < 2048; n += 256) s += ws[WS_C1MAX_F + n * 64 + c];
    red[t] = s;
    __syncthreads();
    for (int k = 128; k > 0; k >>= 1) {
        if (t < k) red[t] += red[t + k];
        __syncthreads();
    }
    if (t == 0) ws[WS_STAT2 + c] = red[0] * (1.f / 2048.f);
}

// conv2 SCINOL weights -> bf16 in MFMA fragment order [uv][kc][ot][quad][m16][j]
__global__ void k_prepw2(const float* __restrict__ w0, const float* __restrict__ S2,
                         const float* __restrict__ G, const float* __restrict__ eta,
                         const float* __restrict__ wM,
                         const float* __restrict__ b0, const float* __restrict__ bS2,
                         const float* __restrict__ bG, const float* __restrict__ beta,
                         float* ws, __hip_bfloat16* __restrict__ wp2) {
    int i = blockIdx.x * 256 + threadIdx.x;  // exactly 102400
    int j = i & 7, m16 = (i >> 3) & 15, quad = (i >> 7) & 3;
    int ot = (i >> 9) & 3, kc = (i >> 11) & 1, uv = i >> 12;
    int oc = ot * 16 + m16, ic = kc * 32 + quad * 8 + j;
    int s = oc * 1600 + ic * 25 + uv;
    float M = fmaxf(ws[WS_STAT2 + ic], wM[ic]);
    float g = G[s];
    float den = sqrtf(S2[s] + M * M);
    float inv = 1.f / den;
    float th = fminf(fmaxf(g * inv, -1.f), 1.f);
    float v = w0[s] + ((g != 0.f) ? th * 0.5f * inv * eta[s] : 0.f);
    wp2[i] = __float2bfloat16(v);
    if (blockIdx.x == 0 && threadIdx.x < 64) {
        int c = threadIdx.x;
        float gb = bG[c];
        float den2 = sqrtf(bS2[c] + 1.f);
        float inv2 = 1.f / den2;
        float th2 = fminf(fmaxf(gb * inv2, -1.f), 1.f);
        ws[WS_B2 + c] = b0[c] + ((gb != 0.f) ? th2 * 0.5f * inv2 * beta[c] : 0.f);
    }
}

// async 16B/lane prefetch of one 8KB weight tap into LDS (wave-uniform lds base)
__device__ __forceinline__ void prefetch_tap(const ushort* __restrict__ wp2,
                                             ushort* swbuf, int uv, int wv, int lane) {
    const char* g = (const char*)wp2 + uv * 8192 + wv * 1024 + lane * 16;
    char* l = (char*)swbuf + wv * 1024;
#pragma unroll
    for (int j = 0; j < 4; ++j)
        __builtin_amdgcn_global_load_lds(
            (const __attribute__((address_space(1))) unsigned*)(g + j * 2048),
            (__attribute__((address_space(3))) unsigned*)(l + j * 2048),
            16, 0, 0);
}

// conv2 implicit GEMM. Block = 128 thr (2 waves) = 2 images, wave = 1 image.
// A from LDS (padded stride 72), B double-buffered in LDS via async global_load_lds,
// fragment-order weight layout -> conflict-free B reads; one barrier per uv.
__global__ void __launch_bounds__(128)
k_conv2(const ushort* __restrict__ pool1, const ushort* __restrict__ wp2,
        const float* __restrict__ ws, float* __restrict__ pool2) {
    __shared__ __align__(16) ushort sImg[2 * 10368];  // 2 images, 144 rows x 72 (pad)
    __shared__ __align__(16) ushort sW[2][4096];      // double-buffered tap
    int tid = threadIdx.x;
    int wv = tid >> 6, lane = tid & 63;
    int n0 = blockIdx.x * 2;

    {   // stage 2 images: 288 rows x 8 uint4 chunks, padded dst stride 9 uint4
        const uint4* src = (const uint4*)(pool1 + (size_t)n0 * 9216);
        uint4* dst = (uint4*)sImg;
#pragma unroll
        for (int i = 0; i < 18; ++i) {
            int c = tid + i * 128;          // 0..2303
            dst[(c >> 3) * 9 + (c & 7)] = src[c];
        }
    }
    prefetch_tap(wp2, sW[0], 0, wv, lane);

    int m16 = lane & 15, quad = lane >> 4;
    int q8 = quad * 8;
    int x0 = m16 & 7;
    int yb = m16 >> 3;
    v4f acc[4][4];
#pragma unroll
    for (int i = 0; i < 4; ++i)
#pragma unroll
        for (int j = 0; j < 4; ++j) acc[i][j] = (v4f){0.f, 0.f, 0.f, 0.f};

    __syncthreads();  // drains staging stores + prefetch(0)

    const ushort* simg = sImg + wv * 10368;
    for (int uvIdx = 0; uvIdx < 25; ++uvIdx) {
        if (uvIdx < 24) prefetch_tap(wp2, sW[(uvIdx + 1) & 1], uvIdx + 1, wv, lane);
        int u = (uvIdx * 13) >> 6;       // uvIdx / 5
        int v = uvIdx - u * 5;
        v8s a[2][4], bf[2][4];
#pragma unroll
        for (int kc = 0; kc < 2; ++kc)
#pragma unroll
            for (int pt = 0; pt < 4; ++pt)
                a[kc][pt] = *(const v8s*)(simg +
                    ((pt * 2 + yb + u) * 12 + x0 + v) * 72 + kc * 32 + q8);
        const ushort* wb = sW[uvIdx & 1];
#pragma unroll
        for (int kc = 0; kc < 2; ++kc)
#pragma unroll
            for (int ot = 0; ot < 4; ++ot)
                bf[kc][ot] = *(const v8s*)(wb + (((kc * 4 + ot) * 4 + quad) * 16 + m16) * 8);
#pragma unroll
        for (int kc = 0; kc < 2; ++kc)
#pragma unroll
            for (int pt = 0; pt < 4; ++pt)
#pragma unroll
                for (int ot = 0; ot < 4; ++ot)
                    acc[pt][ot] = __builtin_amdgcn_mfma_f32_16x16x32_bf16(
                        a[kc][pt], bf[kc][ot], acc[pt][ot], 0, 0, 0);
        __syncthreads();  // drains prefetch(uv+1); all waves done with sW[uv&1]
    }

    // epilogue: bias + relu + 2x2 maxpool -> pooled2[n][oc*16+py*4+px] fp32
    int n = n0 + wv;
    float bv[4];
#pragma unroll
    for (int ot = 0; ot < 4; ++ot) bv[ot] = ws[WS_B2 + ot * 16 + m16];
    float* outp = pool2 + (size_t)n * 1024;
#pragma unroll
    for (int pt = 0; pt < 4; ++pt)
#pragma unroll
        for (int ot = 0; ot < 4; ++ot) {
            v4f a = acc[pt][ot];
            float m01 = fmaxf(a[0], a[1]);
            float m23 = fmaxf(a[2], a[3]);
            m01 = fmaxf(m01, __shfl_xor(m01, 32, 64));
            m23 = fmaxf(m23, __shfl_xor(m23, 32, 64));
            if (lane < 32) {
                int oc = ot * 16 + m16;
                int f = oc * 16 + pt * 4 + (quad & 1) * 2;
                outp[f] = fmaxf(m01 + bv[ot], 0.f);
                outp[f + 1] = fmaxf(m23 + bv[ot], 0.f);
            }
        }
}

// per-feature partial sums over batch (h >= 0 so |h| = h); 64 blocks x 32 images,
// plain stores to per-block slots (NO atomics).
__global__ void k_statl(const float* __restrict__ pool2, float* ws) {
    int b = blockIdx.x, tid = threadIdx.x;
    float4 s = {0.f, 0.f, 0.f, 0.f};
    for (int im = 0; im < 32; ++im) {
        float4 v = ((const float4*)(pool2 + (size_t)(b * 32 + im) * 1024))[tid];
        s.x += v.x; s.y += v.y; s.z += v.z; s.w += v.w;
    }
    ((float4*)(ws + WS_LPART_F + b * 1024))[tid] = s;
}

// reduce the 64 partials per feature -> WS_STATL. 4 blocks x 256 = 1024 threads.
__global__ void k_statlred(float* ws) {
    int f = blockIdx.x * 256 + threadIdx.x;
    float s = 0.f;
#pragma unroll
    for (int b = 0; b < 64; ++b) s += ws[WS_LPART_F + b * 1024 + f];
    ws[WS_STATL + f] = s;
}

__global__ void k_prepwl(const float* __restrict__ w0, const float* __restrict__ S2,
                         const float* __restrict__ G, const float* __restrict__ eta,
                         const float* __restrict__ wM,
                         const float* __restrict__ b0, const float* __restrict__ bS2,
                         const float* __restrict__ bG, const float* __restrict__ beta,
                         float* ws) {
    int i = blockIdx.x * 256 + threadIdx.x;
    if (i < 10240) {
        int f = i & 1023;
        float stat = ws[WS_STATL + f] * (1.f / 2048.f);
        float M = fmaxf(wM[i], stat);
        float s2 = S2[i];
        float den = sqrtf(s2 + M * M);
        float inv = 1.f / den;
        float th = fminf(fmaxf(G[i] * inv, -1.f), 1.f);
        ws[WS_WL + i] = w0[i] + ((s2 != 0.f) ? th * 0.5f * inv * eta[i] : 0.f);  // cond = wS2 != 0
    } else if (i < 10250) {
        int c = i - 10240;
        float s2 = bS2[c];
        float den = sqrtf(s2 + 1.f);
        float inv = 1.f / den;
        float th = fminf(fmaxf(bG[c] * inv, -1.f), 1.f);
        ws[WS_BL + c] = b0[c] + ((s2 != 0.f) ? th * 0.5f * inv * beta[c] : 0.f);  // cond = bS2 != 0
    }
}

// (2048,1024) x (1024,10)^T + b: wave per image, lane-strided features
__global__ void k_linear(const float* __restrict__ pool2, const float* __restrict__ ws,
                         float* __restrict__ out) {
    int tid = threadIdx.x;
    int wv = tid >> 6, lane = tid & 63;
    int n = blockIdx.x * 4 + wv;
    const float* hp = pool2 + (size_t)n * 1024;
    float h[16];
#pragma unroll
    for (int j = 0; j < 16; ++j) h[j] = hp[j * 64 + lane];
    for (int oc = 0; oc < 10; ++oc) {
        const float* wp = ws + WS_WL + oc * 1024;
        float d = 0.f;
#pragma unroll
        for (int j = 0; j < 16; ++j) d = fmaf(h[j], wp[j * 64 + lane], d);
#pragma unroll
        for (int off = 32; off; off >>= 1) d += __shfl_xor(d, off, 64);
        if (lane == 0) out[n * 10 + oc] = d + ws[WS_BL + oc];
    }
}

extern "C" void kernel_launch(void* const* d_in, const int* in_sizes, int n_in,
                              void* d_out, int out_size, void* d_ws, size_t ws_size,
                              hipStream_t stream) {
    const float* x = (const float*)d_in[0];
    float* ws = (float*)d_ws;
    __hip_bfloat16* wp2 = (__hip_bfloat16*)((char*)d_ws + WS_WP2_B);
    __hip_bfloat16* p1 = (__hip_bfloat16*)((char*)d_ws + WS_P1_B);
    float* p2 = (float*)((char*)d_ws + WS_P2_B);
    float* out = (float*)d_out;

    k_stat1<<<512, 256, 0, stream>>>(x, ws);
    k_prepw1<<<17, 256, 0, stream>>>(
        (const float*)d_in[1], (const float*)d_in[2], (const float*)d_in[3],
        (const float*)d_in[4], (const float*)d_in[5], (const float*)d_in[6],
        (const float*)d_in[7], (const float*)d_in[8], (const float*)d_in[9], ws);
    k_conv1<<<2048, 256, 0, stream>>>(x, ws, p1);
    k_stat2red<<<64, 256, 0, stream>>>(ws);
    k_prepw2<<<400, 256, 0, stream>>>(
        (const float*)d_in[10], (const float*)d_in[11], (const float*)d_in[12],
        (const float*)d_in[13], (const float*)d_in[14], (const float*)d_in[15],
        (const float*)d_in[16], (const float*)d_in[17], (const float*)d_in[18], ws, wp2);
    k_conv2<<<1024, 128, 0, stream>>>((const ushort*)p1, (const ushort*)wp2, ws, p2);
    k_statl<<<64, 256, 0, stream>>>(p2, ws);
    k_statlred<<<4, 256, 0, stream>>>(ws);
    k_prepwl<<<41, 256, 0, stream>>>(
        (const float*)d_in[19], (const float*)d_in[20], (const float*)d_in[21],
        (const float*)d_in[22], (const float*)d_in[23], (const float*)d_in[24],
        (const float*)d_in[25], (const float*)d_in[26], (const float*)d_in[27], ws);
    k_linear<<<512, 256, 0, stream>>>(p2, ws, out);
}

// Round 6
// 208.027 us; speedup vs baseline: 1.4224x; 1.0583x over previous
//
#include <hip/hip_runtime.h>
#include <hip/hip_bf16.h>

typedef float v4f __attribute__((ext_vector_type(4)));
typedef short v8s __attribute__((ext_vector_type(8)));

// ---- workspace layout ----
// float indices:
#define WS_STAT2   0        // 64   conv2 per-ic mean-of-max
#define WS_STATL   64       // 1024 (unused now; kept for layout stability)
#define WS_B1      1088     // 64
#define WS_B2      1152     // 64
#define WS_WL      1216     // 10240
#define WS_BL      11456    // 10
#define WS_IMAX    11520    // 2048 per-image max|x|
// byte offsets:
#define WS_W1F_B   54272    // 4096 bf16 conv1 weight frags [ot][q][m16][j], oc = m16*4+ot
#define WS_WP2_B   62464    // 25*64*64 bf16 conv2 weights, fragment order [uv][kc][ot][quad][m16][j]
#define WS_P1_B    267264   // 2048*144*64 bf16 pooled1 NHWC
#define WS_P2_B    38016000 // 2048*1024 fp32 pooled2
// scratch aliases (stream-ordered reuse, no extra footprint):
#define WS_C1MAX_F 9504000  // = P2 base as float idx; conv1 per-image ch-max [n][64]
#define WS_LPART_F 66816    // = P1 base as float idx; statl partials [64][1024]
// total ~46.4 MB (unchanged)

// per-image max|x|: 512 blocks x 4 waves, wave = 1 image.
__global__ void k_stat1(const float* __restrict__ x, float* ws) {
    int tid = threadIdx.x;
    int wv = tid >> 6, lane = tid & 63;
    int n = blockIdx.x * 4 + wv;
    const float* p = x + n * 784;
    float m = 0.f;
    for (int i = lane; i < 784; i += 64) m = fmaxf(m, fabsf(p[i]));
#pragma unroll
    for (int off = 32; off; off >>= 1) m = fmaxf(m, __shfl_xor(m, off, 64));
    if (lane == 0) ws[WS_IMAX + n] = m;
}

// conv1 SCINOL weights -> bf16 B-fragments [ot][q][m16][j] with oc = m16*4+ot
__global__ void k_prepw1(const float* __restrict__ w0, const float* __restrict__ S2,
                         const float* __restrict__ G, const float* __restrict__ eta,
                         const float* __restrict__ wM,
                         const float* __restrict__ b0, const float* __restrict__ bS2,
                         const float* __restrict__ bG, const float* __restrict__ beta,
                         float* ws) {
    __shared__ float red[256];
    int tid = threadIdx.x;
    float p = 0.f;
    for (int i = tid; i < 2048; i += 256) p += ws[WS_IMAX + i];
    red[tid] = p;
    __syncthreads();
    for (int s = 128; s > 0; s >>= 1) {
        if (tid < s) red[tid] += red[tid + s];
        __syncthreads();
    }
    float M = fmaxf(red[0] * (1.f / 2048.f), wM[0]);

    int i = blockIdx.x * 256 + tid;
    if (i < 4096) {
        int j = i & 7, m16 = (i >> 3) & 15, q = (i >> 7) & 3, ot = i >> 9;
        int tap = q * 8 + j, oc = m16 * 4 + ot;
        float v = 0.f;
        if (tap < 25) {
            int s = oc * 25 + tap;
            float g = G[s];
            float den = sqrtf(S2[s] + M * M);
            float inv = 1.f / den;
            float th = fminf(fmaxf(g * inv, -1.f), 1.f);
            v = w0[s] + ((g != 0.f) ? th * 0.5f * inv * eta[s] : 0.f);
        }
        ((__hip_bfloat16*)((char*)ws + WS_W1F_B))[i] = __float2bfloat16(v);
    } else if (i < 4160) {
        int c = i - 4096;
        float g = bG[c];
        float den = sqrtf(bS2[c] + 1.f);
        float inv = 1.f / den;
        float th = fminf(fmaxf(g * inv, -1.f), 1.f);
        ws[WS_B1 + c] = b0[c] + ((g != 0.f) ? th * 0.5f * inv * beta[c] : 0.f);
    }
}

// conv1 via MFMA implicit GEMM. Block = 256 thr (4 waves) = 1 image.
__global__ void __launch_bounds__(256)
k_conv1(const float* __restrict__ x, float* ws, __hip_bfloat16* __restrict__ pool1) {
    __shared__ __align__(16) float sX[1024];   // 28x28 image + zero pad
    __shared__ int sMax[64];
    int n = blockIdx.x, tid = threadIdx.x;
    int wv = tid >> 6, lane = tid & 63;
    int m16 = lane & 15, quad = lane >> 4;

    {   // stage image (784 floats) + zero pad to 1024
        const float4* src = (const float4*)(x + (size_t)n * 784);
        float4 v = {0.f, 0.f, 0.f, 0.f};
        if (tid < 196) v = src[tid];
        ((float4*)sX)[tid] = v;
    }
    if (tid < 64) sMax[tid] = 0;

    const ushort* wfrag = (const ushort*)((const char*)ws + WS_W1F_B);
    v8s bfr[4];
#pragma unroll
    for (int ot = 0; ot < 4; ++ot)
        bfr[ot] = *(const v8s*)(wfrag + ((ot * 4 + quad) * 16 + m16) * 8);
    float4 bias = *(const float4*)(ws + WS_B1 + m16 * 4);

    int dj[8];
#pragma unroll
    for (int j = 0; j < 8; ++j) {
        int tap = quad * 8 + j;
        int u = (tap * 13) >> 6;
        dj[j] = tap + 23 * u;
    }

    int W0 = wv * 36 + (m16 >> 2);
    int wy = (W0 * 171) >> 11;
    int wx = W0 - wy * 12;
    int coff = 28 * ((m16 >> 1) & 1) + (m16 & 1);

    __syncthreads();

    float vmax[4] = {0.f, 0.f, 0.f, 0.f};
    ushort* op = (ushort*)(pool1 + (size_t)n * 9216);

    float g[8];
    {
        int base = 56 * wy + 2 * wx + coff;
#pragma unroll
        for (int j = 0; j < 8; ++j) g[j] = sX[base + dj[j]];
    }
    for (int mt = 0; mt < 9; ++mt) {
        union { v8s v; ushort us[8]; } ua;
#pragma unroll
        for (int j = 0; j < 8; ++j)
            ua.us[j] = __bfloat16_as_ushort(__float2bfloat16(g[j]));

        wx += 4;
        if (wx >= 12) { wx -= 12; ++wy; }
        if (mt < 8) {
            int nb = 56 * wy + 2 * wx + coff;
#pragma unroll
            for (int j = 0; j < 8; ++j) g[j] = sX[nb + dj[j]];
        }

        v4f z = {0.f, 0.f, 0.f, 0.f};
        v4f acc[4];
#pragma unroll
        for (int ot = 0; ot < 4; ++ot)
            acc[ot] = __builtin_amdgcn_mfma_f32_16x16x32_bf16(ua.v, bfr[ot], z, 0, 0, 0);

        int Wd = (wv * 9 + mt) * 4 + quad;
        ushort4 pk;
#pragma unroll
        for (int ot = 0; ot < 4; ++ot) {
            v4f a = acc[ot];
            float m = fmaxf(fmaxf(a[0], a[1]), fmaxf(a[2], a[3]));
            float pv = fmaxf(m + bias[ot], 0.f);
            vmax[ot] = fmaxf(vmax[ot], pv);
            ((ushort*)&pk)[ot] = __bfloat16_as_ushort(__float2bfloat16(pv));
        }
        *(ushort4*)(op + Wd * 64 + m16 * 4) = pk;
    }

#pragma unroll
    for (int ot = 0; ot < 4; ++ot) {
        float m = vmax[ot];
        m = fmaxf(m, __shfl_xor(m, 16, 64));
        m = fmaxf(m, __shfl_xor(m, 32, 64));
        if (lane < 16) atomicMax(&sMax[lane * 4 + ot], __float_as_int(m));
    }
    __syncthreads();
    if (tid < 64) ws[WS_C1MAX_F + n * 64 + tid] = __int_as_float(sMax[tid]);
}

// reduce conv1 per-image channel maxima -> per-channel batch mean. 64 blocks, 1/ch.
__global__ void k_stat2red(float* ws) {
    __shared__ float red[256];
    int c = blockIdx.x, t = threadIdx.x;
    float s = 0.f;
    for (int n = t; n < 2048; n += 256) s += ws[WS_C1MAX_F + n * 64 + c];
    red[t] = s;
    __syncthreads();
    for (int k = 128; k > 0; k >>= 1) {
        if (t < k) red[t] += red[t + k];
        __syncthreads();
    }
    if (t == 0) ws[WS_STAT2 + c] = red[0] * (1.f / 2048.f);
}

// conv2 SCINOL weights -> bf16 in MFMA fragment order [uv][kc][ot][quad][m16][j]
__global__ void k_prepw2(const float* __restrict__ w0, const float* __restrict__ S2,
                         const float* __restrict__ G, const float* __restrict__ eta,
                         const float* __restrict__ wM,
                         const float* __restrict__ b0, const float* __restrict__ bS2,
                         const float* __restrict__ bG, const float* __restrict__ beta,
                         float* ws, __hip_bfloat16* __restrict__ wp2) {
    int i = blockIdx.x * 256 + threadIdx.x;  // exactly 102400
    int j = i & 7, m16 = (i >> 3) & 15, quad = (i >> 7) & 3;
    int ot = (i >> 9) & 3, kc = (i >> 11) & 1, uv = i >> 12;
    int oc = ot * 16 + m16, ic = kc * 32 + quad * 8 + j;
    int s = oc * 1600 + ic * 25 + uv;
    float M = fmaxf(ws[WS_STAT2 + ic], wM[ic]);
    float g = G[s];
    float den = sqrtf(S2[s] + M * M);
    float inv = 1.f / den;
    float th = fminf(fmaxf(g * inv, -1.f), 1.f);
    float v = w0[s] + ((g != 0.f) ? th * 0.5f * inv * eta[s] : 0.f);
    wp2[i] = __float2bfloat16(v);
    if (blockIdx.x == 0 && threadIdx.x < 64) {
        int c = threadIdx.x;
        float gb = bG[c];
        float den2 = sqrtf(bS2[c] + 1.f);
        float inv2 = 1.f / den2;
        float th2 = fminf(fmaxf(gb * inv2, -1.f), 1.f);
        ws[WS_B2 + c] = b0[c] + ((gb != 0.f) ? th2 * 0.5f * inv2 * beta[c] : 0.f);
    }
}

// conv2 implicit GEMM. Block = 128 thr (2 waves) = 2 images, wave = 1 image.
// A from LDS (padded stride 72). B-fragments are register double-buffered,
// prefetched one uv ahead via coalesced GLOBAL loads (1KB/wave each, L2-hot:
// every wave reads the same 200KB). NO barriers in the K-loop -> the 6
// resident waves/CU co-schedule MFMA freely.
__global__ void __launch_bounds__(128)
k_conv2(const ushort* __restrict__ pool1, const ushort* __restrict__ wp2,
        const float* __restrict__ ws, float* __restrict__ pool2) {
    __shared__ __align__(16) ushort sImg[2 * 10368];  // 2 images, 144 rows x 72 (pad)
    int tid = threadIdx.x;
    int wv = tid >> 6, lane = tid & 63;
    int n0 = blockIdx.x * 2;

    {   // stage 2 images: 288 rows x 8 uint4 chunks, padded dst stride 9 uint4
        const uint4* src = (const uint4*)(pool1 + (size_t)n0 * 9216);
        uint4* dst = (uint4*)sImg;
#pragma unroll
        for (int i = 0; i < 18; ++i) {
            int c = tid + i * 128;          // 0..2303
            dst[(c >> 3) * 9 + (c & 7)] = src[c];
        }
    }

    int m16 = lane & 15, quad = lane >> 4;
    int q8 = quad * 8;
    int x0 = m16 & 7;
    int yb = m16 >> 3;
    v4f acc[4][4];
#pragma unroll
    for (int i = 0; i < 4; ++i)
#pragma unroll
        for (int j = 0; j < 4; ++j) acc[i][j] = (v4f){0.f, 0.f, 0.f, 0.f};

    // B-frag global base: offset = uv*4096 + (kc*4+ot)*512 + lane*8 (ushorts)
    const ushort* wlane = wp2 + lane * 8;
    v8s bf[2][2][4];
#pragma unroll
    for (int kc = 0; kc < 2; ++kc)
#pragma unroll
        for (int ot = 0; ot < 4; ++ot)
            bf[0][kc][ot] = *(const v8s*)(wlane + (kc * 4 + ot) * 512);

    __syncthreads();  // image staging only — the last barrier in this kernel

    const ushort* simg = sImg + wv * 10368;
#pragma unroll
    for (int uvIdx = 0; uvIdx < 25; ++uvIdx) {
        int cur = uvIdx & 1, nxt = cur ^ 1;
        if (uvIdx < 24) {
            const ushort* wnext = wlane + (uvIdx + 1) * 4096;
#pragma unroll
            for (int kc = 0; kc < 2; ++kc)
#pragma unroll
                for (int ot = 0; ot < 4; ++ot)
                    bf[nxt][kc][ot] = *(const v8s*)(wnext + (kc * 4 + ot) * 512);
        }
        int u = (uvIdx * 13) >> 6;       // uvIdx / 5
        int v = uvIdx - u * 5;
        v8s a[2][4];
#pragma unroll
        for (int kc = 0; kc < 2; ++kc)
#pragma unroll
            for (int pt = 0; pt < 4; ++pt)
                a[kc][pt] = *(const v8s*)(simg +
                    ((pt * 2 + yb + u) * 12 + x0 + v) * 72 + kc * 32 + q8);
#pragma unroll
        for (int kc = 0; kc < 2; ++kc)
#pragma unroll
            for (int pt = 0; pt < 4; ++pt)
#pragma unroll
                for (int ot = 0; ot < 4; ++ot)
                    acc[pt][ot] = __builtin_amdgcn_mfma_f32_16x16x32_bf16(
                        a[kc][pt], bf[cur][kc][ot], acc[pt][ot], 0, 0, 0);
    }

    // epilogue: bias + relu + 2x2 maxpool -> pooled2[n][oc*16+py*4+px] fp32
    int n = n0 + wv;
    float bv[4];
#pragma unroll
    for (int ot = 0; ot < 4; ++ot) bv[ot] = ws[WS_B2 + ot * 16 + m16];
    float* outp = pool2 + (size_t)n * 1024;
#pragma unroll
    for (int pt = 0; pt < 4; ++pt)
#pragma unroll
        for (int ot = 0; ot < 4; ++ot) {
            v4f a = acc[pt][ot];
            float m01 = fmaxf(a[0], a[1]);
            float m23 = fmaxf(a[2], a[3]);
            m01 = fmaxf(m01, __shfl_xor(m01, 32, 64));
            m23 = fmaxf(m23, __shfl_xor(m23, 32, 64));
            if (lane < 32) {
                int oc = ot * 16 + m16;
                int f = oc * 16 + pt * 4 + (quad & 1) * 2;
                outp[f] = fmaxf(m01 + bv[ot], 0.f);
                outp[f + 1] = fmaxf(m23 + bv[ot], 0.f);
            }
        }
}

// per-feature partial sums over batch; 64 blocks x 32 images, plain stores.
__global__ void k_statl(const float* __restrict__ pool2, float* ws) {
    int b = blockIdx.x, tid = threadIdx.x;
    float4 s = {0.f, 0.f, 0.f, 0.f};
    for (int im = 0; im < 32; ++im) {
        float4 v = ((const float4*)(pool2 + (size_t)(b * 32 + im) * 1024))[tid];
        s.x += v.x; s.y += v.y; s.z += v.z; s.w += v.w;
    }
    ((float4*)(ws + WS_LPART_F + b * 1024))[tid] = s;
}

// linear weights; folds the 64-partial statl reduction inline (no separate kernel)
__global__ void k_prepwl(const float* __restrict__ w0, const float* __restrict__ S2,
                         const float* __restrict__ G, const float* __restrict__ eta,
                         const float* __restrict__ wM,
                         const float* __restrict__ b0, const float* __restrict__ bS2,
                         const float* __restrict__ bG, const float* __restrict__ beta,
                         float* ws) {
    int i = blockIdx.x * 256 + threadIdx.x;
    if (i < 10240) {
        int f = i & 1023;
        float s = 0.f;
#pragma unroll
        for (int b = 0; b < 64; ++b) s += ws[WS_LPART_F + b * 1024 + f];
        float stat = s * (1.f / 2048.f);
        float M = fmaxf(wM[i], stat);
        float s2 = S2[i];
        float den = sqrtf(s2 + M * M);
        float inv = 1.f / den;
        float th = fminf(fmaxf(G[i] * inv, -1.f), 1.f);
        ws[WS_WL + i] = w0[i] + ((s2 != 0.f) ? th * 0.5f * inv * eta[i] : 0.f);  // cond = wS2 != 0
    } else if (i < 10250) {
        int c = i - 10240;
        float s2 = bS2[c];
        float den = sqrtf(s2 + 1.f);
        float inv = 1.f / den;
        float th = fminf(fmaxf(bG[c] * inv, -1.f), 1.f);
        ws[WS_BL + c] = b0[c] + ((s2 != 0.f) ? th * 0.5f * inv * beta[c] : 0.f);  // cond = bS2 != 0
    }
}

// (2048,1024) x (1024,10)^T + b: wave per image, lane-strided features
__global__ void k_linear(const float* __restrict__ pool2, const float* __restrict__ ws,
                         float* __restrict__ out) {
    int tid = threadIdx.x;
    int wv = tid >> 6, lane = tid & 63;
    int n = blockIdx.x * 4 + wv;
    const float* hp = pool2 + (size_t)n * 1024;
    float h[16];
#pragma unroll
    for (int j = 0; j < 16; ++j) h[j] = hp[j * 64 + lane];
    for (int oc = 0; oc < 10; ++oc) {
        const float* wp = ws + WS_WL + oc * 1024;
        float d = 0.f;
#pragma unroll
        for (int j = 0; j < 16; ++j) d = fmaf(h[j], wp[j * 64 + lane], d);
#pragma unroll
        for (int off = 32; off; off >>= 1) d += __shfl_xor(d, off, 64);
        if (lane == 0) out[n * 10 + oc] = d + ws[WS_BL + oc];
    }
}

extern "C" void kernel_launch(void* const* d_in, const int* in_sizes, int n_in,
                              void* d_out, int out_size, void* d_ws, size_t ws_size,
                              hipStream_t stream) {
    const float* x = (const float*)d_in[0];
    float* ws = (float*)d_ws;
    __hip_bfloat16* wp2 = (__hip_bfloat16*)((char*)d_ws + WS_WP2_B);
    __hip_bfloat16* p1 = (__hip_bfloat16*)((char*)d_ws + WS_P1_B);
    float* p2 = (float*)((char*)d_ws + WS_P2_B);
    float* out = (float*)d_out;

    k_stat1<<<512, 256, 0, stream>>>(x, ws);
    k_prepw1<<<17, 256, 0, stream>>>(
        (const float*)d_in[1], (const float*)d_in[2], (const float*)d_in[3],
        (const float*)d_in[4], (const float*)d_in[5], (const float*)d_in[6],
        (const float*)d_in[7], (const float*)d_in[8], (const float*)d_in[9], ws);
    k_conv1<<<2048, 256, 0, stream>>>(x, ws, p1);
    k_stat2red<<<64, 256, 0, stream>>>(ws);
    k_prepw2<<<400, 256, 0, stream>>>(
        (const float*)d_in[10], (const float*)d_in[11], (const float*)d_in[12],
        (const float*)d_in[13], (const float*)d_in[14], (const float*)d_in[15],
        (const float*)d_in[16], (const float*)d_in[17], (const float*)d_in[18], ws, wp2);
    k_conv2<<<1024, 128, 0, stream>>>((const ushort*)p1, (const ushort*)wp2, ws, p2);
    k_statl<<<64, 256, 0, stream>>>(p2, ws);
    k_prepwl<<<41, 256, 0, stream>>>(
        (const float*)d_in[19], (const float*)d_in[20], (const float*)d_in[21],
        (const float*)d_in[22], (const float*)d_in[23], (const float*)d_in[24],
        (const float*)d_in[25], (const float*)d_in[26], (const float*)d_in[27], ws);
    k_linear<<<512, 256, 0, stream>>>(p2, ws, out);
}